// Round 3
// baseline (13065.356 us; speedup 1.0000x reference)
//
#include <hip/hip_runtime.h>

#define D 64            // FEAT
#define BSH 7           // bin shift
#define BW_ 128         // nodes per bin = 1<<BSH
#define NBLK 256        // binning blocks
#define NBIN_MAX 1024   // supports N <= 131072

// ---------------------------------------------------------------- relu: x = max(h,0)
__global__ void relu_k(const float* __restrict__ h, float* __restrict__ x, int n) {
    int i = blockIdx.x * blockDim.x + threadIdx.x;
    if (i < n) x[i] = fmaxf(h[i], 0.0f);
}

// ---------------------------------------------------------------- pass A: per-block coarse histograms (dst-bin AND src-bin)
__global__ void binA_k(const int* __restrict__ src, const int* __restrict__ dst,
                       int* __restrict__ cntD, int* __restrict__ cntS,
                       int E, int nbin, int chunk) {
    __shared__ int hD[NBIN_MAX], hS[NBIN_MAX];
    int tid = threadIdx.x, b = blockIdx.x;
    for (int i = tid; i < nbin; i += 256) { hD[i] = 0; hS[i] = 0; }
    __syncthreads();
    int k1 = min(E, (b + 1) * chunk);
    for (int k = b * chunk + tid; k < k1; k += 256) {
        atomicAdd(&hD[dst[k] >> BSH], 1);
        atomicAdd(&hS[src[k] >> BSH], 1);
    }
    __syncthreads();
    for (int i = tid; i < nbin; i += 256) {
        cntD[i * NBLK + b] = hD[i];   // [bin][blk] layout -> coalesced in B1
        cntS[i * NBLK + b] = hS[i];
    }
}

// ---------------------------------------------------------------- pass B1: per-bin exclusive scan over blocks (+ bin totals)
__global__ void binB1_k(int* __restrict__ cntD, int* __restrict__ cntS,
                        int* __restrict__ totD, int* __restrict__ totS, int nbin) {
    int bin = blockIdx.x, tid = threadIdx.x;
    int* cnt = blockIdx.y ? cntS : cntD;
    int* tot = blockIdx.y ? totS : totD;
    __shared__ int tmp[NBLK];
    int v = cnt[bin * NBLK + tid];
    tmp[tid] = v;
    __syncthreads();
    for (int off = 1; off < NBLK; off <<= 1) {
        int t = (tid >= off) ? tmp[tid - off] : 0;
        __syncthreads();
        tmp[tid] += t;
        __syncthreads();
    }
    cnt[bin * NBLK + tid] = tmp[tid] - v; // exclusive within bin
    if (tid == NBLK - 1) tot[bin] = tmp[tid];
}

// ---------------------------------------------------------------- pass B2: scan bin totals -> bin start offsets (+sentinel)
__global__ void binB2_k(const int* __restrict__ totD, const int* __restrict__ totS,
                        int* __restrict__ startD, int* __restrict__ startS,
                        int nbin, int E) {
    __shared__ int tmp[NBIN_MAX];
    int tid = threadIdx.x; // 1024
    {
        int v = (tid < nbin) ? totD[tid] : 0;
        tmp[tid] = v;
        __syncthreads();
        for (int off = 1; off < NBIN_MAX; off <<= 1) {
            int t = (tid >= off) ? tmp[tid - off] : 0;
            __syncthreads();
            tmp[tid] += t;
            __syncthreads();
        }
        if (tid < nbin) startD[tid] = tmp[tid] - v;
        if (tid == 0) startD[nbin] = E;
        __syncthreads();
    }
    {
        int v = (tid < nbin) ? totS[tid] : 0;
        tmp[tid] = v;
        __syncthreads();
        for (int off = 1; off < NBIN_MAX; off <<= 1) {
            int t = (tid >= off) ? tmp[tid - off] : 0;
            __syncthreads();
            tmp[tid] += t;
            __syncthreads();
        }
        if (tid < nbin) startS[tid] = tmp[tid] - v;
        if (tid == 0) startS[nbin] = E;
    }
}

// ---------------------------------------------------------------- pass C: scatter edges into bins (LDS fill counters, no global atomics)
// bsd[pos] = src | (dstLocal<<17)   (src<2^17, dstLocal<128 -> 24 bits)
__global__ void binC_k(const int* __restrict__ src, const int* __restrict__ dst,
                       const int* __restrict__ cntD, const int* __restrict__ cntS,
                       const int* __restrict__ startD, const int* __restrict__ startS,
                       unsigned int* __restrict__ bsd, unsigned char* __restrict__ bss,
                       int E, int nbin, int chunk) {
    __shared__ int baseD[NBIN_MAX], baseS[NBIN_MAX];
    int tid = threadIdx.x, b = blockIdx.x;
    for (int i = tid; i < nbin; i += 256) {
        baseD[i] = startD[i] + cntD[i * NBLK + b];
        baseS[i] = startS[i] + cntS[i * NBLK + b];
    }
    __syncthreads();
    int k1 = min(E, (b + 1) * chunk);
    for (int k = b * chunk + tid; k < k1; k += 256) {
        int s = src[k], d = dst[k];
        int pD = atomicAdd(&baseD[d >> BSH], 1);
        bsd[pD] = (unsigned)s | ((unsigned)(d & (BW_ - 1)) << 17);
        int pS = atomicAdd(&baseS[s >> BSH], 1);
        bss[pS] = (unsigned char)(s & (BW_ - 1));
    }
}

// ---------------------------------------------------------------- out-degree per node via per-src-bin LDS histogram -> norm_out
__global__ void outdeg_k(const unsigned char* __restrict__ bss, const int* __restrict__ startS,
                         float* __restrict__ nout, int N) {
    int b = blockIdx.x, tid = threadIdx.x;
    __shared__ int h[BW_];
    if (tid < BW_) h[tid] = 0;
    __syncthreads();
    int k1 = startS[b + 1];
    for (int k = startS[b] + tid; k < k1; k += 256) atomicAdd(&h[bss[k]], 1);
    __syncthreads();
    if (tid < BW_) {
        int n = b * BW_ + tid;
        if (n < N) nout[n] = rsqrtf(fmaxf((float)h[tid], 1.0f));
    }
}

// ---------------------------------------------------------------- pull step: one block per 128-node bin, LDS accumulators
// out[n] = 0.9*nin[n] * sum_e nout[src_e]*feat[src_e]  +  0.1*x[n]
// (in-degree recomputed in LDS each step -> nin on the fly; no CSR, no atomics to HBM)
__global__ void pullbin_k(const unsigned int* __restrict__ bsd, const int* __restrict__ startD,
                          const float* __restrict__ nout, const float* __restrict__ feat,
                          const float* __restrict__ x, float* __restrict__ out, int N) {
    int b = blockIdx.x, tid = threadIdx.x;
    __shared__ float acc[BW_ * D];   // 32 KB
    __shared__ int hist[BW_];
    for (int i = tid; i < BW_ * D; i += 256) acc[i] = 0.0f;
    if (tid < BW_) hist[tid] = 0;
    __syncthreads();
    int kb = startD[b], ke = startD[b + 1];
    int lane = tid & 63, wv = tid >> 6;
    int len = ke - kb, per = (len + 3) >> 2;
    int k = kb + wv * per;
    int kend = min(ke, k + per);
    for (; k + 2 <= kend; k += 2) {          // 2-deep unroll: independent gather chains
        unsigned e0 = bsd[k], e1 = bsd[k + 1];
        int s0 = e0 & 0x1FFFF, s1 = e1 & 0x1FFFF;
        float w0 = nout[s0], w1 = nout[s1];
        float f0 = feat[(size_t)s0 * D + lane];
        float f1 = feat[(size_t)s1 * D + lane];
        atomicAdd(&acc[(e0 >> 17) * D + lane], w0 * f0);
        atomicAdd(&acc[(e1 >> 17) * D + lane], w1 * f1);
        if (lane == 0) { atomicAdd(&hist[e0 >> 17], 1); atomicAdd(&hist[e1 >> 17], 1); }
    }
    if (k < kend) {
        unsigned e = bsd[k];
        int s = e & 0x1FFFF;
        atomicAdd(&acc[(e >> 17) * D + lane], nout[s] * feat[(size_t)s * D + lane]);
        if (lane == 0) atomicAdd(&hist[e >> 17], 1);
    }
    __syncthreads();
    size_t n0 = (size_t)b * BW_;
    for (int i = tid; i < BW_ * D; i += 256) {
        int nl = i >> 6;
        size_t n = n0 + nl;
        if (n < (size_t)N) {
            float nin9 = 0.9f * rsqrtf(fmaxf((float)hist[nl], 1.0f));
            size_t gi = n * D + (i & 63);
            out[gi] = nin9 * acc[i] + 0.1f * x[gi];
        }
    }
}

// ---------------------------------------------------------------- fusion: W1 in LDS, 16 nodes per block, 1 atomic/block
__global__ void fusion_k(const float* __restrict__ z, const float* __restrict__ W1,
                         const float* __restrict__ b1, const float* __restrict__ W2,
                         float* __restrict__ wsum, int N) {
    __shared__ float W1s[D * 128];
    __shared__ float zs[16][D];
    int j = threadIdx.x; // 0..127 = hidden unit
    for (int k = j; k < D * 128; k += 128) W1s[k] = W1[k];
    int p = blockIdx.y;
    int n0 = blockIdx.x * 16;
    int nn = min(16, N - n0);
    const float* zb = z + ((size_t)p * N + n0) * D;
    for (int k = j; k < nn * D; k += 128) zs[k >> 6][k & (D - 1)] = zb[k];
    __syncthreads();
    float bj = b1[j], w2j = W2[j];
    float part = 0.f;
    for (int n = 0; n < nn; ++n) {
        float acc = bj;
#pragma unroll
        for (int k = 0; k < D; ++k) acc += zs[n][k] * W1s[k * 128 + j];
        part += tanhf(acc);
    }
    part *= w2j;
#pragma unroll
    for (int off = 32; off > 0; off >>= 1) part += __shfl_down(part, off, 64);
    __shared__ float ps[2];
    if ((j & 63) == 0) ps[j >> 6] = part;
    __syncthreads();
    if (j == 0) atomicAdd(&wsum[p], ps[0] + ps[1]);
}

// ---------------------------------------------------------------- beta = softmax(wsum / N)
__global__ void beta_k(const float* __restrict__ wsum, float* __restrict__ beta, float invN) {
    float w0 = wsum[0] * invN, w1 = wsum[1] * invN, w2 = wsum[2] * invN;
    float m = fmaxf(w0, fmaxf(w1, w2));
    float e0 = expf(w0 - m), e1 = expf(w1 - m), e2 = expf(w2 - m);
    float s = e0 + e1 + e2;
    beta[0] = e0 / s; beta[1] = e1 / s; beta[2] = e2 / s;
}

// ---------------------------------------------------------------- out = sum_p beta[p] * z[p]
__global__ void final_k(const float* __restrict__ z, const float* __restrict__ beta,
                        float* __restrict__ out, int n, size_t NF) {
    int i = blockIdx.x * blockDim.x + threadIdx.x;
    if (i < n) out[i] = beta[0] * z[i] + beta[1] * z[i + NF] + beta[2] * z[i + 2 * NF];
}

extern "C" void kernel_launch(void* const* d_in, const int* in_sizes, int n_in,
                              void* d_out, int out_size, void* d_ws, size_t ws_size,
                              hipStream_t stream) {
    const float* h   = (const float*)d_in[0];
    const int*   src = (const int*)d_in[1];
    const int*   dst = (const int*)d_in[2];
    const float* W1  = (const float*)d_in[3];
    const float* b1  = (const float*)d_in[4];
    const float* W2  = (const float*)d_in[5];

    const int P = 3;
    const int N = in_sizes[0] / D;           // 100000
    const int E = in_sizes[1] / P;           // 3200000
    const size_t NF = (size_t)N * D;         // 6.4M floats
    const int nf = (int)NF;
    const int nbin = (N + BW_ - 1) >> BSH;   // 782
    const int chunk = (E + NBLK - 1) / NBLK; // 12500

    // workspace layout (bytes)
    char* base = (char*)d_ws;
    float* z = (float*)base;            base += 3 * NF * sizeof(float);
    float* S = (float*)base;            base += NF * sizeof(float);
    unsigned int* bsd = (unsigned int*)base; base += (size_t)E * 4;
    unsigned char* bss = (unsigned char*)base; base += ((size_t)E + 255) & ~(size_t)255;
    int* cntD = (int*)base;             base += (size_t)NBIN_MAX * NBLK * 4;
    int* cntS = (int*)base;             base += (size_t)NBIN_MAX * NBLK * 4;
    int* totD = (int*)base;             base += NBIN_MAX * 4;
    int* totS = (int*)base;             base += NBIN_MAX * 4;
    int* startD = (int*)base;           base += (NBIN_MAX + 1) * 4;
    int* startS = (int*)base;           base += (NBIN_MAX + 1) * 4;
    float* nout = (float*)base;         base += (size_t)N * 4;
    float* wsum = (float*)base;         base += 4 * 4;
    float* beta = (float*)base;

    float* x = (float*)d_out; // d_out doubles as relu(h) buffer until final_k

    relu_k<<<(nf + 255) / 256, 256, 0, stream>>>(h, x, nf);

    for (int p = 0; p < P; ++p) {
        const int* sp = src + (size_t)p * E;
        const int* dp = dst + (size_t)p * E;

        binA_k<<<NBLK, 256, 0, stream>>>(sp, dp, cntD, cntS, E, nbin, chunk);
        dim3 gB1(nbin, 2);
        binB1_k<<<gB1, NBLK, 0, stream>>>(cntD, cntS, totD, totS, nbin);
        binB2_k<<<1, NBIN_MAX, 0, stream>>>(totD, totS, startD, startS, nbin, E);
        binC_k<<<NBLK, 256, 0, stream>>>(sp, dp, cntD, cntS, startD, startS, bsd, bss, E, nbin, chunk);
        outdeg_k<<<nbin, 256, 0, stream>>>(bss, startS, nout, N);

        float* zp = z + (size_t)p * NF;
        // ping-pong: x -> zp -> S -> zp (result lands in zp)
        const float* fin[3]  = {x, zp, S};
        float*       fout[3] = {zp, S, zp};
        for (int step = 0; step < 3; ++step) {
            pullbin_k<<<nbin, 256, 0, stream>>>(bsd, startD, nout, fin[step], x, fout[step], N);
        }
    }

    hipMemsetAsync(wsum, 0, 4 * sizeof(float), stream);
    dim3 fgrid((N + 15) / 16, P);
    fusion_k<<<fgrid, 128, 0, stream>>>(z, W1, b1, W2, wsum, N);
    beta_k<<<1, 1, 0, stream>>>(wsum, beta, 1.0f / (float)N);
    final_k<<<(nf + 255) / 256, 256, 0, stream>>>(z, beta, (float*)d_out, nf, NF);
}

// Round 4
// 1882.273 us; speedup vs baseline: 6.9413x; 6.9413x over previous
//
#include <hip/hip_runtime.h>

#define D 64            // FEAT
#define BSH 7           // bin shift
#define BW_ 128         // nodes per bin
#define NBLK 256        // binning blocks
#define NBIN_MAX 1024   // supports N <= 131072

// ---------------------------------------------------------------- relu (float4)
__global__ void relu_k(const float4* __restrict__ h, float4* __restrict__ x, int n4) {
    int i = blockIdx.x * blockDim.x + threadIdx.x;
    if (i < n4) {
        float4 v = h[i];
        v.x = fmaxf(v.x, 0.f); v.y = fmaxf(v.y, 0.f);
        v.z = fmaxf(v.z, 0.f); v.w = fmaxf(v.w, 0.f);
        x[i] = v;
    }
}

// ---------------------------------------------------------------- pass A: per-block coarse histograms (dst-bin AND src-bin)
__global__ void binA_k(const int* __restrict__ src, const int* __restrict__ dst,
                       int* __restrict__ cntD, int* __restrict__ cntS,
                       int E, int nbin, int chunk) {
    __shared__ int hD[NBIN_MAX], hS[NBIN_MAX];
    int tid = threadIdx.x, b = blockIdx.x;
    for (int i = tid; i < nbin; i += 256) { hD[i] = 0; hS[i] = 0; }
    __syncthreads();
    int k1 = min(E, (b + 1) * chunk);
    for (int k = b * chunk + tid; k < k1; k += 256) {
        atomicAdd(&hD[dst[k] >> BSH], 1);
        atomicAdd(&hS[src[k] >> BSH], 1);
    }
    __syncthreads();
    for (int i = tid; i < nbin; i += 256) {
        cntD[i * NBLK + b] = hD[i];
        cntS[i * NBLK + b] = hS[i];
    }
}

// ---------------------------------------------------------------- pass B1: per-bin exclusive scan over blocks (+ totals)
__global__ void binB1_k(int* __restrict__ cntD, int* __restrict__ cntS,
                        int* __restrict__ totD, int* __restrict__ totS, int nbin) {
    int bin = blockIdx.x, tid = threadIdx.x;
    int* cnt = blockIdx.y ? cntS : cntD;
    int* tot = blockIdx.y ? totS : totD;
    __shared__ int tmp[NBLK];
    int v = cnt[bin * NBLK + tid];
    tmp[tid] = v;
    __syncthreads();
    for (int off = 1; off < NBLK; off <<= 1) {
        int t = (tid >= off) ? tmp[tid - off] : 0;
        __syncthreads();
        tmp[tid] += t;
        __syncthreads();
    }
    cnt[bin * NBLK + tid] = tmp[tid] - v;
    if (tid == NBLK - 1) tot[bin] = tmp[tid];
}

// ---------------------------------------------------------------- pass B2: scan bin totals -> bin starts (+sentinel)
__global__ void binB2_k(const int* __restrict__ totD, const int* __restrict__ totS,
                        int* __restrict__ startD, int* __restrict__ startS,
                        int nbin, int E) {
    __shared__ int tmp[NBIN_MAX];
    int tid = threadIdx.x; // 1024
    {
        int v = (tid < nbin) ? totD[tid] : 0;
        tmp[tid] = v;
        __syncthreads();
        for (int off = 1; off < NBIN_MAX; off <<= 1) {
            int t = (tid >= off) ? tmp[tid - off] : 0;
            __syncthreads();
            tmp[tid] += t;
            __syncthreads();
        }
        if (tid < nbin) startD[tid] = tmp[tid] - v;
        if (tid == 0) startD[nbin] = E;
        __syncthreads();
    }
    {
        int v = (tid < nbin) ? totS[tid] : 0;
        tmp[tid] = v;
        __syncthreads();
        for (int off = 1; off < NBIN_MAX; off <<= 1) {
            int t = (tid >= off) ? tmp[tid - off] : 0;
            __syncthreads();
            tmp[tid] += t;
            __syncthreads();
        }
        if (tid < nbin) startS[tid] = tmp[tid] - v;
        if (tid == 0) startS[nbin] = E;
    }
}

// ---------------------------------------------------------------- pass C: scatter edges into bins (LDS fill counters only)
// bsd[pos] = src | (dstLocal<<17)
__global__ void binC_k(const int* __restrict__ src, const int* __restrict__ dst,
                       const int* __restrict__ cntD, const int* __restrict__ cntS,
                       const int* __restrict__ startD, const int* __restrict__ startS,
                       unsigned int* __restrict__ bsd, unsigned char* __restrict__ bss,
                       int E, int nbin, int chunk) {
    __shared__ int baseD[NBIN_MAX], baseS[NBIN_MAX];
    int tid = threadIdx.x, b = blockIdx.x;
    for (int i = tid; i < nbin; i += 256) {
        baseD[i] = startD[i] + cntD[i * NBLK + b];
        baseS[i] = startS[i] + cntS[i * NBLK + b];
    }
    __syncthreads();
    int k1 = min(E, (b + 1) * chunk);
    for (int k = b * chunk + tid; k < k1; k += 256) {
        int s = src[k], d = dst[k];
        int pD = atomicAdd(&baseD[d >> BSH], 1);
        bsd[pD] = (unsigned)s | ((unsigned)(d & (BW_ - 1)) << 17);
        int pS = atomicAdd(&baseS[s >> BSH], 1);
        bss[pS] = (unsigned char)(s & (BW_ - 1));
    }
}

// ---------------------------------------------------------------- out-degree -> norm_out
__global__ void outdeg_k(const unsigned char* __restrict__ bss, const int* __restrict__ startS,
                         float* __restrict__ nout, int N) {
    int b = blockIdx.x, tid = threadIdx.x;
    __shared__ int h[BW_];
    if (tid < BW_) h[tid] = 0;
    __syncthreads();
    int k1 = startS[b + 1];
    for (int k = startS[b] + tid; k < k1; k += 256) atomicAdd(&h[bss[k]], 1);
    __syncthreads();
    if (tid < BW_) {
        int n = b * BW_ + tid;
        if (n < N) nout[n] = rsqrtf(fmaxf((float)h[tid], 1.0f));
    }
}

// ---------------------------------------------------------------- per-bin counting sort -> true CSR (no global atomics)
// also emits rowptr and nin9 = 0.9 * norm_in
__global__ void csr_k(const unsigned int* __restrict__ bsd, const int* __restrict__ startD,
                      int* __restrict__ ssrc, int* __restrict__ rowptr,
                      float* __restrict__ nin9, int N, int E) {
    __shared__ int hist[BW_], tmp[BW_], excl[BW_], fill[BW_];
    int b = blockIdx.x, tid = threadIdx.x;
    if (tid < BW_) { hist[tid] = 0; fill[tid] = 0; }
    __syncthreads();
    int kb = startD[b], ke = startD[b + 1];
    for (int k = kb + tid; k < ke; k += 256) atomicAdd(&hist[bsd[k] >> 17], 1);
    __syncthreads();
    if (tid < BW_) tmp[tid] = hist[tid];
    __syncthreads();
    for (int off = 1; off < BW_; off <<= 1) {
        int t = (tid < BW_ && tid >= off) ? tmp[tid - off] : 0;
        __syncthreads();
        if (tid < BW_) tmp[tid] += t;
        __syncthreads();
    }
    if (tid < BW_) excl[tid] = tmp[tid] - hist[tid];
    __syncthreads();
    for (int k = kb + tid; k < ke; k += 256) {
        unsigned e = bsd[k];
        int dl = e >> 17;
        int r = atomicAdd(&fill[dl], 1);
        ssrc[kb + excl[dl] + r] = (int)(e & 0x1FFFF);
    }
    if (tid < BW_) {
        int n = b * BW_ + tid;
        if (n < N) {
            rowptr[n] = kb + excl[tid];
            nin9[n] = 0.9f * rsqrtf(fmaxf((float)hist[tid], 1.0f));
        }
    }
    if (b == 0 && tid == 0) rowptr[N] = E;
}

// ---------------------------------------------------------------- featS = nout[node] * feat   (float4)
__global__ void prescale_k(const float4* __restrict__ in, const float* __restrict__ nout,
                           float4* __restrict__ out, int n4) {
    int i = blockIdx.x * blockDim.x + threadIdx.x;
    if (i < n4) {
        float w = nout[i >> 4]; // 16 float4 per node
        float4 v = in[i];
        v.x *= w; v.y *= w; v.z *= w; v.w *= w;
        out[i] = v;
    }
}

// ---------------------------------------------------------------- CSR pull: one wave/node, 4 edges x 16 lanes x float4
// raw = sum_e featS[src_e]; z = nin9[n]*raw + 0.1*x[n]; out = doScale ? nout[n]*z : z
__global__ void pull2_k(const int* __restrict__ rowptr, const int* __restrict__ ssrc,
                        const float* __restrict__ featS, const float* __restrict__ x,
                        const float* __restrict__ nin9, const float* __restrict__ nout,
                        float* __restrict__ out, int N, int doScale) {
    int wid = (blockIdx.x * blockDim.x + threadIdx.x) >> 6;
    if (wid >= N) return;
    int lane = threadIdx.x & 63;
    int slot = lane >> 4;           // 0..3 : which edge in the group of 4
    int fl = (lane & 15) << 2;      // feature offset (float4)
    int kb = rowptr[wid], ke = rowptr[wid + 1];
    float a0 = 0.f, a1 = 0.f, a2 = 0.f, a3 = 0.f;
    for (int k = kb + slot; k < ke; k += 4) {
        int s = ssrc[k];
        const float4 f = *(const float4*)(featS + (size_t)s * D + fl);
        a0 += f.x; a1 += f.y; a2 += f.z; a3 += f.w;
    }
    // reduce the 4 slots (lanes l, l^16, l^32, l^48 hold same features)
    a0 += __shfl_xor(a0, 16, 64); a1 += __shfl_xor(a1, 16, 64);
    a2 += __shfl_xor(a2, 16, 64); a3 += __shfl_xor(a3, 16, 64);
    a0 += __shfl_xor(a0, 32, 64); a1 += __shfl_xor(a1, 32, 64);
    a2 += __shfl_xor(a2, 32, 64); a3 += __shfl_xor(a3, 32, 64);
    if (slot == 0) {
        size_t gi = (size_t)wid * D + fl;
        float4 xv = *(const float4*)(x + gi);
        float nn = nin9[wid];
        float sc = doScale ? nout[wid] : 1.0f;
        float4 r;
        r.x = sc * (nn * a0 + 0.1f * xv.x);
        r.y = sc * (nn * a1 + 0.1f * xv.y);
        r.z = sc * (nn * a2 + 0.1f * xv.z);
        r.w = sc * (nn * a3 + 0.1f * xv.w);
        *(float4*)(out + gi) = r;
    }
}

// ---------------------------------------------------------------- fusion: W1 in LDS, 16 nodes/block, 1 atomic/block
__global__ void fusion_k(const float* __restrict__ z, const float* __restrict__ W1,
                         const float* __restrict__ b1, const float* __restrict__ W2,
                         float* __restrict__ wsum, int N) {
    __shared__ float W1s[D * 128];
    __shared__ float zs[16][D];
    int j = threadIdx.x;
    for (int k = j; k < D * 128; k += 128) W1s[k] = W1[k];
    int p = blockIdx.y;
    int n0 = blockIdx.x * 16;
    int nn = min(16, N - n0);
    const float* zb = z + ((size_t)p * N + n0) * D;
    for (int k = j; k < nn * D; k += 128) zs[k >> 6][k & (D - 1)] = zb[k];
    __syncthreads();
    float bj = b1[j], w2j = W2[j];
    float part = 0.f;
    for (int n = 0; n < nn; ++n) {
        float acc = bj;
#pragma unroll
        for (int k = 0; k < D; ++k) acc += zs[n][k] * W1s[k * 128 + j];
        part += tanhf(acc);
    }
    part *= w2j;
#pragma unroll
    for (int off = 32; off > 0; off >>= 1) part += __shfl_down(part, off, 64);
    __shared__ float ps[2];
    if ((j & 63) == 0) ps[j >> 6] = part;
    __syncthreads();
    if (j == 0) atomicAdd(&wsum[p], ps[0] + ps[1]);
}

// ---------------------------------------------------------------- beta = softmax(wsum / N)
__global__ void beta_k(const float* __restrict__ wsum, float* __restrict__ beta, float invN) {
    float w0 = wsum[0] * invN, w1 = wsum[1] * invN, w2 = wsum[2] * invN;
    float m = fmaxf(w0, fmaxf(w1, w2));
    float e0 = expf(w0 - m), e1 = expf(w1 - m), e2 = expf(w2 - m);
    float s = e0 + e1 + e2;
    beta[0] = e0 / s; beta[1] = e1 / s; beta[2] = e2 / s;
}

// ---------------------------------------------------------------- out = sum_p beta[p] * z[p]  (float4)
__global__ void final_k(const float4* __restrict__ z, const float* __restrict__ beta,
                        float4* __restrict__ out, int n4, size_t NF4) {
    int i = blockIdx.x * blockDim.x + threadIdx.x;
    if (i < n4) {
        float b0 = beta[0], b1v = beta[1], b2 = beta[2];
        float4 z0 = z[i], z1 = z[i + NF4], z2 = z[i + 2 * NF4];
        float4 r;
        r.x = b0 * z0.x + b1v * z1.x + b2 * z2.x;
        r.y = b0 * z0.y + b1v * z1.y + b2 * z2.y;
        r.z = b0 * z0.z + b1v * z1.z + b2 * z2.z;
        r.w = b0 * z0.w + b1v * z1.w + b2 * z2.w;
        out[i] = r;
    }
}

extern "C" void kernel_launch(void* const* d_in, const int* in_sizes, int n_in,
                              void* d_out, int out_size, void* d_ws, size_t ws_size,
                              hipStream_t stream) {
    const float* h   = (const float*)d_in[0];
    const int*   src = (const int*)d_in[1];
    const int*   dst = (const int*)d_in[2];
    const float* W1  = (const float*)d_in[3];
    const float* b1  = (const float*)d_in[4];
    const float* W2  = (const float*)d_in[5];

    const int P = 3;
    const int N = in_sizes[0] / D;           // 100000
    const int E = in_sizes[1] / P;           // 3200000
    const size_t NF = (size_t)N * D;
    const int nf = (int)NF, n4 = nf / 4;
    const int nbin = (N + BW_ - 1) >> BSH;   // 782
    const int chunk = (E + NBLK - 1) / NBLK;

    // workspace layout (bytes), ~119 MB + z reuse:
    // z[3*NF] | featA[NF] | featB[NF] | ssrc[E] (bss aliases) | cntD | cntS | tot/start | nout | nin9 | rowptr | wsum | beta
    char* base = (char*)d_ws;
    float* z     = (float*)base;  base += 3 * NF * sizeof(float);
    float* featA = (float*)base;  base += NF * sizeof(float);
    float* featB = (float*)base;  base += NF * sizeof(float);
    int*   ssrc  = (int*)base;    base += (size_t)E * 4;
    int*   cntD  = (int*)base;    base += (size_t)NBIN_MAX * NBLK * 4;
    int*   cntS  = (int*)base;    base += (size_t)NBIN_MAX * NBLK * 4;
    int*   totD  = (int*)base;    base += NBIN_MAX * 4;
    int*   totS  = (int*)base;    base += NBIN_MAX * 4;
    int*   startD = (int*)base;   base += (NBIN_MAX + 1) * 4;
    int*   startS = (int*)base;   base += (NBIN_MAX + 1) * 4;
    float* nout  = (float*)base;  base += (size_t)N * 4;
    float* nin9  = (float*)base;  base += (size_t)N * 4;
    int*   rowptr = (int*)base;   base += ((size_t)N + 1) * 4;
    float* wsum  = (float*)base;  base += 16;
    float* beta  = (float*)base;

    unsigned char* bss = (unsigned char*)ssrc; // dead before ssrc is written (csr_k after outdeg_k)

    float* x = (float*)d_out; // relu(h) lives in d_out until final_k

    relu_k<<<(n4 + 255) / 256, 256, 0, stream>>>((const float4*)h, (float4*)x, n4);

    for (int p = 0; p < P; ++p) {
        const int* sp = src + (size_t)p * E;
        const int* dp = dst + (size_t)p * E;
        float* zp = z + (size_t)p * NF;
        unsigned int* bsd = (unsigned int*)zp; // zp is dead until step-2 writes it; bsd dead by then

        binA_k<<<NBLK, 256, 0, stream>>>(sp, dp, cntD, cntS, E, nbin, chunk);
        dim3 gB1(nbin, 2);
        binB1_k<<<gB1, NBLK, 0, stream>>>(cntD, cntS, totD, totS, nbin);
        binB2_k<<<1, NBIN_MAX, 0, stream>>>(totD, totS, startD, startS, nbin, E);
        binC_k<<<NBLK, 256, 0, stream>>>(sp, dp, cntD, cntS, startD, startS, bsd, bss, E, nbin, chunk);
        outdeg_k<<<nbin, 256, 0, stream>>>(bss, startS, nout, N);
        csr_k<<<nbin, 256, 0, stream>>>(bsd, startD, ssrc, rowptr, nin9, N, E);

        prescale_k<<<(n4 + 255) / 256, 256, 0, stream>>>((const float4*)x, nout, (float4*)featA, n4);

        int pgrid = (N + 3) / 4; // 4 waves (nodes) per 256-thread block
        pull2_k<<<pgrid, 256, 0, stream>>>(rowptr, ssrc, featA, x, nin9, nout, featB, N, 1);
        pull2_k<<<pgrid, 256, 0, stream>>>(rowptr, ssrc, featB, x, nin9, nout, featA, N, 1);
        pull2_k<<<pgrid, 256, 0, stream>>>(rowptr, ssrc, featA, x, nin9, nout, zp,    N, 0);
    }

    hipMemsetAsync(wsum, 0, 4 * sizeof(float), stream);
    dim3 fgrid((N + 15) / 16, P);
    fusion_k<<<fgrid, 128, 0, stream>>>(z, W1, b1, W2, wsum, N);
    beta_k<<<1, 1, 0, stream>>>(wsum, beta, 1.0f / (float)N);
    final_k<<<(n4 + 255) / 256, 256, 0, stream>>>((const float4*)z, beta, (float4*)d_out, n4, NF / 4);
}

// Round 6
// 1603.464 us; speedup vs baseline: 8.1482x; 1.1739x over previous
//
#include <hip/hip_runtime.h>

#define D 64            // FEAT
#define BSH 7           // bin shift
#define BW_ 128         // nodes per bin
#define NBLK 256        // binning blocks
#define NBIN_MAX 1024   // supports N <= 131072

typedef __attribute__((ext_vector_type(8))) short bfrag;   // 8 bf16 (4 VGPR)
typedef __attribute__((ext_vector_type(4))) float ffrag;   // 4 f32 acc

__device__ __forceinline__ short f2bf(float f) {
    unsigned u = __builtin_bit_cast(unsigned, f);
    u = (u + 0x7FFFu + ((u >> 16) & 1u)) >> 16;   // RNE
    return (short)u;
}
__device__ __forceinline__ float tanh_fast(float x) {
    float e = __expf(2.0f * x);
    return 1.0f - 2.0f / (e + 1.0f);   // exact limits at +-inf
}

// ---------------------------------------------------------------- relu (float4)
__global__ void relu_k(const float4* __restrict__ h, float4* __restrict__ x, int n4) {
    int i = blockIdx.x * blockDim.x + threadIdx.x;
    if (i < n4) {
        float4 v = h[i];
        v.x = fmaxf(v.x, 0.f); v.y = fmaxf(v.y, 0.f);
        v.z = fmaxf(v.z, 0.f); v.w = fmaxf(v.w, 0.f);
        x[i] = v;
    }
}

// ---------------------------------------------------------------- pass A: per-block coarse histograms (dst-bin AND src-bin)
__global__ void binA_k(const int* __restrict__ src, const int* __restrict__ dst,
                       int* __restrict__ cntD, int* __restrict__ cntS,
                       int E, int nbin, int chunk) {
    __shared__ int hD[NBIN_MAX], hS[NBIN_MAX];
    int tid = threadIdx.x, b = blockIdx.x;
    for (int i = tid; i < nbin; i += 256) { hD[i] = 0; hS[i] = 0; }
    __syncthreads();
    int k1 = min(E, (b + 1) * chunk);
    for (int k = b * chunk + tid; k < k1; k += 256) {
        atomicAdd(&hD[dst[k] >> BSH], 1);
        atomicAdd(&hS[src[k] >> BSH], 1);
    }
    __syncthreads();
    for (int i = tid; i < nbin; i += 256) {
        cntD[i * NBLK + b] = hD[i];
        cntS[i * NBLK + b] = hS[i];
    }
}

// ---------------------------------------------------------------- pass B1: per-bin exclusive scan over blocks (+ totals)
__global__ void binB1_k(int* __restrict__ cntD, int* __restrict__ cntS,
                        int* __restrict__ totD, int* __restrict__ totS, int nbin) {
    int bin = blockIdx.x, tid = threadIdx.x;
    int* cnt = blockIdx.y ? cntS : cntD;
    int* tot = blockIdx.y ? totS : totD;
    __shared__ int tmp[NBLK];
    int v = cnt[bin * NBLK + tid];
    tmp[tid] = v;
    __syncthreads();
    for (int off = 1; off < NBLK; off <<= 1) {
        int t = (tid >= off) ? tmp[tid - off] : 0;
        __syncthreads();
        tmp[tid] += t;
        __syncthreads();
    }
    cnt[bin * NBLK + tid] = tmp[tid] - v;
    if (tid == NBLK - 1) tot[bin] = tmp[tid];
}

// ---------------------------------------------------------------- pass B2: scan bin totals -> bin starts (+sentinel)
__global__ void binB2_k(const int* __restrict__ totD, const int* __restrict__ totS,
                        int* __restrict__ startD, int* __restrict__ startS,
                        int nbin, int E) {
    __shared__ int tmp[NBIN_MAX];
    int tid = threadIdx.x; // 1024
    {
        int v = (tid < nbin) ? totD[tid] : 0;
        tmp[tid] = v;
        __syncthreads();
        for (int off = 1; off < NBIN_MAX; off <<= 1) {
            int t = (tid >= off) ? tmp[tid - off] : 0;
            __syncthreads();
            tmp[tid] += t;
            __syncthreads();
        }
        if (tid < nbin) startD[tid] = tmp[tid] - v;
        if (tid == 0) startD[nbin] = E;
        __syncthreads();
    }
    {
        int v = (tid < nbin) ? totS[tid] : 0;
        tmp[tid] = v;
        __syncthreads();
        for (int off = 1; off < NBIN_MAX; off <<= 1) {
            int t = (tid >= off) ? tmp[tid - off] : 0;
            __syncthreads();
            tmp[tid] += t;
            __syncthreads();
        }
        if (tid < nbin) startS[tid] = tmp[tid] - v;
        if (tid == 0) startS[nbin] = E;
    }
}

// ---------------------------------------------------------------- pass C: scatter edges into bins (LDS fill counters only)
__global__ void binC_k(const int* __restrict__ src, const int* __restrict__ dst,
                       const int* __restrict__ cntD, const int* __restrict__ cntS,
                       const int* __restrict__ startD, const int* __restrict__ startS,
                       unsigned int* __restrict__ bsd, unsigned char* __restrict__ bss,
                       int E, int nbin, int chunk) {
    __shared__ int baseD[NBIN_MAX], baseS[NBIN_MAX];
    int tid = threadIdx.x, b = blockIdx.x;
    for (int i = tid; i < nbin; i += 256) {
        baseD[i] = startD[i] + cntD[i * NBLK + b];
        baseS[i] = startS[i] + cntS[i * NBLK + b];
    }
    __syncthreads();
    int k1 = min(E, (b + 1) * chunk);
    for (int k = b * chunk + tid; k < k1; k += 256) {
        int s = src[k], d = dst[k];
        int pD = atomicAdd(&baseD[d >> BSH], 1);
        bsd[pD] = (unsigned)s | ((unsigned)(d & (BW_ - 1)) << 17);
        int pS = atomicAdd(&baseS[s >> BSH], 1);
        bss[pS] = (unsigned char)(s & (BW_ - 1));
    }
}

// ---------------------------------------------------------------- out-degree -> norm_out
__global__ void outdeg_k(const unsigned char* __restrict__ bss, const int* __restrict__ startS,
                         float* __restrict__ nout, int N) {
    int b = blockIdx.x, tid = threadIdx.x;
    __shared__ int h[BW_];
    if (tid < BW_) h[tid] = 0;
    __syncthreads();
    int k1 = startS[b + 1];
    for (int k = startS[b] + tid; k < k1; k += 256) atomicAdd(&h[bss[k]], 1);
    __syncthreads();
    if (tid < BW_) {
        int n = b * BW_ + tid;
        if (n < N) nout[n] = rsqrtf(fmaxf((float)h[tid], 1.0f));
    }
}

// ---------------------------------------------------------------- per-bin counting sort -> true CSR
__global__ void csr_k(const unsigned int* __restrict__ bsd, const int* __restrict__ startD,
                      int* __restrict__ ssrc, int* __restrict__ rowptr,
                      float* __restrict__ nin9, int N, int E) {
    __shared__ int hist[BW_], tmp[BW_], excl[BW_], fill[BW_];
    int b = blockIdx.x, tid = threadIdx.x;
    if (tid < BW_) { hist[tid] = 0; fill[tid] = 0; }
    __syncthreads();
    int kb = startD[b], ke = startD[b + 1];
    for (int k = kb + tid; k < ke; k += 256) atomicAdd(&hist[bsd[k] >> 17], 1);
    __syncthreads();
    if (tid < BW_) tmp[tid] = hist[tid];
    __syncthreads();
    for (int off = 1; off < BW_; off <<= 1) {
        int t = (tid < BW_ && tid >= off) ? tmp[tid - off] : 0;
        __syncthreads();
        if (tid < BW_) tmp[tid] += t;
        __syncthreads();
    }
    if (tid < BW_) excl[tid] = tmp[tid] - hist[tid];
    __syncthreads();
    for (int k = kb + tid; k < ke; k += 256) {
        unsigned e = bsd[k];
        int dl = e >> 17;
        int r = atomicAdd(&fill[dl], 1);
        ssrc[kb + excl[dl] + r] = (int)(e & 0x1FFFF);
    }
    if (tid < BW_) {
        int n = b * BW_ + tid;
        if (n < N) {
            rowptr[n] = kb + excl[tid];
            nin9[n] = 0.9f * rsqrtf(fmaxf((float)hist[tid], 1.0f));
        }
    }
    if (b == 0 && tid == 0) rowptr[N] = E;
}

// ---------------------------------------------------------------- featS = nout[node] * feat   (float4)
__global__ void prescale_k(const float4* __restrict__ in, const float* __restrict__ nout,
                           float4* __restrict__ out, int n4) {
    int i = blockIdx.x * blockDim.x + threadIdx.x;
    if (i < n4) {
        float w = nout[i >> 4];
        float4 v = in[i];
        v.x *= w; v.y *= w; v.z *= w; v.w *= w;
        out[i] = v;
    }
}

// ---------------------------------------------------------------- CSR pull: one wave/node, 8 edges in flight x float4
__global__ void pull2_k(const int* __restrict__ rowptr, const int* __restrict__ ssrc,
                        const float* __restrict__ featS, const float* __restrict__ x,
                        const float* __restrict__ nin9, const float* __restrict__ nout,
                        float* __restrict__ out, int N, int doScale) {
    int wid = (blockIdx.x * blockDim.x + threadIdx.x) >> 6;
    if (wid >= N) return;
    int lane = threadIdx.x & 63;
    int slot = lane >> 4;           // 0..3
    int fl = (lane & 15) << 2;      // feature offset (float4)
    int kb = rowptr[wid], ke = rowptr[wid + 1];
    float a0 = 0.f, a1 = 0.f, a2 = 0.f, a3 = 0.f;
    int k = kb + slot;
    for (; k + 4 < ke; k += 8) {    // 2 edges per slot in flight
        int s0 = ssrc[k], s1 = ssrc[k + 4];
        const float4 f0 = *(const float4*)(featS + (size_t)s0 * D + fl);
        const float4 f1 = *(const float4*)(featS + (size_t)s1 * D + fl);
        a0 += f0.x; a1 += f0.y; a2 += f0.z; a3 += f0.w;
        a0 += f1.x; a1 += f1.y; a2 += f1.z; a3 += f1.w;
    }
    if (k < ke) {
        int s = ssrc[k];
        const float4 f = *(const float4*)(featS + (size_t)s * D + fl);
        a0 += f.x; a1 += f.y; a2 += f.z; a3 += f.w;
    }
    a0 += __shfl_xor(a0, 16, 64); a1 += __shfl_xor(a1, 16, 64);
    a2 += __shfl_xor(a2, 16, 64); a3 += __shfl_xor(a3, 16, 64);
    a0 += __shfl_xor(a0, 32, 64); a1 += __shfl_xor(a1, 32, 64);
    a2 += __shfl_xor(a2, 32, 64); a3 += __shfl_xor(a3, 32, 64);
    if (slot == 0) {
        size_t gi = (size_t)wid * D + fl;
        float4 xv = *(const float4*)(x + gi);
        float nn = nin9[wid];
        float sc = doScale ? nout[wid] : 1.0f;
        float4 r;
        r.x = sc * (nn * a0 + 0.1f * xv.x);
        r.y = sc * (nn * a1 + 0.1f * xv.y);
        r.z = sc * (nn * a2 + 0.1f * xv.z);
        r.w = sc * (nn * a3 + 0.1f * xv.w);
        *(float4*)(out + gi) = r;
    }
}

// ---------------------------------------------------------------- fusion via MFMA: one wave per 16-node tile, all 128 hidden
// part = sum_nodes sum_hidden tanh(z@W1 + b1) * W2 ; per-block partial (no contended atomics)
__global__ void fusion_mfma_k(const float* __restrict__ z, const float* __restrict__ W1,
                              const float* __restrict__ b1v, const float* __restrict__ W2,
                              float* __restrict__ wpart, int N, int nTiles, int npb) {
    int p = blockIdx.y;
    int wv = threadIdx.x >> 6;
    int lane = threadIdx.x & 63;
    int tile = blockIdx.x * 4 + wv;
    float part = 0.0f;
    if (tile < nTiles) {
        int r = lane & 15;      // A row (node) / B,D col (hidden)
        int g = lane >> 4;      // k-group
        size_t node_a = (size_t)tile * 16 + r;
        if (node_a >= (size_t)N) node_a = N - 1;   // tail clamp (masked below)
        const float* zr = z + ((size_t)p * N + node_a) * 64 + g * 8;
        float4 v0 = *(const float4*)(zr);
        float4 v1 = *(const float4*)(zr + 4);
        float4 v2 = *(const float4*)(zr + 32);
        float4 v3 = *(const float4*)(zr + 36);
        bfrag a0, a1;
        a0[0] = f2bf(v0.x); a0[1] = f2bf(v0.y); a0[2] = f2bf(v0.z); a0[3] = f2bf(v0.w);
        a0[4] = f2bf(v1.x); a0[5] = f2bf(v1.y); a0[6] = f2bf(v1.z); a0[7] = f2bf(v1.w);
        a1[0] = f2bf(v2.x); a1[1] = f2bf(v2.y); a1[2] = f2bf(v2.z); a1[3] = f2bf(v2.w);
        a1[4] = f2bf(v3.x); a1[5] = f2bf(v3.y); a1[6] = f2bf(v3.z); a1[7] = f2bf(v3.w);
#pragma unroll 2
        for (int ct = 0; ct < 8; ++ct) {
            int j = ct * 16 + r;
            const float* wp = W1 + (size_t)(g * 8) * 128 + j;   // W1[k][j], k = g*8+e
            bfrag b0, b1f;
#pragma unroll
            for (int e = 0; e < 8; ++e) {
                b0[e]  = f2bf(wp[e * 128]);
                b1f[e] = f2bf(wp[(e + 32) * 128]);
            }
            ffrag acc = {0.f, 0.f, 0.f, 0.f};
            acc = __builtin_amdgcn_mfma_f32_16x16x32_bf16(a0, b0, acc, 0, 0, 0);
            acc = __builtin_amdgcn_mfma_f32_16x16x32_bf16(a1, b1f, acc, 0, 0, 0);
            float bb = b1v[j], w2 = W2[j];
#pragma unroll
            for (int q = 0; q < 4; ++q) {                        // D row = g*4+q
                int node = tile * 16 + g * 4 + q;
                if (node < N) part += w2 * tanh_fast(acc[q] + bb);
            }
        }
    }
#pragma unroll
    for (int off = 1; off < 64; off <<= 1) part += __shfl_xor(part, off, 64);
    __shared__ float ps[4];
    if (lane == 0) ps[wv] = part;
    __syncthreads();
    if (threadIdx.x == 0)
        wpart[(size_t)p * npb + blockIdx.x] = ps[0] + ps[1] + ps[2] + ps[3];
}

// ---------------------------------------------------------------- reduce partials -> beta = softmax(mean)
__global__ void beta2_k(const float* __restrict__ wpart, float* __restrict__ beta,
                        int npb, float invN) {
    int tid = threadIdx.x; // 256
    __shared__ float sums[3];
    __shared__ float ws4[4];
    for (int p = 0; p < 3; ++p) {
        float s = 0.f;
        for (int i = tid; i < npb; i += 256) s += wpart[(size_t)p * npb + i];
#pragma unroll
        for (int off = 1; off < 64; off <<= 1) s += __shfl_xor(s, off, 64);
        if ((tid & 63) == 0) ws4[tid >> 6] = s;
        __syncthreads();
        if (tid == 0) sums[p] = ws4[0] + ws4[1] + ws4[2] + ws4[3];
        __syncthreads();
    }
    if (tid == 0) {
        float w0 = sums[0] * invN, w1 = sums[1] * invN, w2 = sums[2] * invN;
        float m = fmaxf(w0, fmaxf(w1, w2));
        float e0 = expf(w0 - m), e1 = expf(w1 - m), e2 = expf(w2 - m);
        float s = e0 + e1 + e2;
        beta[0] = e0 / s; beta[1] = e1 / s; beta[2] = e2 / s;
    }
}

// ---------------------------------------------------------------- out = sum_p beta[p] * z[p]  (float4)
__global__ void final_k(const float4* __restrict__ z, const float* __restrict__ beta,
                        float4* __restrict__ out, int n4, size_t NF4) {
    int i = blockIdx.x * blockDim.x + threadIdx.x;
    if (i < n4) {
        float b0 = beta[0], b1v = beta[1], b2 = beta[2];
        float4 z0 = z[i], z1 = z[i + NF4], z2 = z[i + 2 * NF4];
        float4 r;
        r.x = b0 * z0.x + b1v * z1.x + b2 * z2.x;
        r.y = b0 * z0.y + b1v * z1.y + b2 * z2.y;
        r.z = b0 * z0.z + b1v * z1.z + b2 * z2.z;
        r.w = b0 * z0.w + b1v * z1.w + b2 * z2.w;
        out[i] = r;
    }
}

extern "C" void kernel_launch(void* const* d_in, const int* in_sizes, int n_in,
                              void* d_out, int out_size, void* d_ws, size_t ws_size,
                              hipStream_t stream) {
    const float* h   = (const float*)d_in[0];
    const int*   src = (const int*)d_in[1];
    const int*   dst = (const int*)d_in[2];
    const float* W1  = (const float*)d_in[3];
    const float* b1  = (const float*)d_in[4];
    const float* W2  = (const float*)d_in[5];

    const int P = 3;
    const int N = in_sizes[0] / D;           // 100000
    const int E = in_sizes[1] / P;           // 3200000
    const size_t NF = (size_t)N * D;
    const int nf = (int)NF, n4 = nf / 4;
    const int nbin = (N + BW_ - 1) >> BSH;   // 782
    const int chunk = (E + NBLK - 1) / NBLK;
    const int nTiles = (N + 15) / 16;        // 6250
    const int npb = (nTiles + 3) / 4;        // fusion blocks per path

    // workspace layout (bytes)
    char* base = (char*)d_ws;
    float* z     = (float*)base;  base += 3 * NF * sizeof(float);
    float* featA = (float*)base;  base += NF * sizeof(float);
    float* featB = (float*)base;  base += NF * sizeof(float);
    int*   ssrc  = (int*)base;    base += (size_t)E * 4;
    int*   cntD  = (int*)base;    base += (size_t)NBIN_MAX * NBLK * 4;
    int*   cntS  = (int*)base;    base += (size_t)NBIN_MAX * NBLK * 4;
    int*   totD  = (int*)base;    base += NBIN_MAX * 4;
    int*   totS  = (int*)base;    base += NBIN_MAX * 4;
    int*   startD = (int*)base;   base += (NBIN_MAX + 1) * 4;
    int*   startS = (int*)base;   base += (NBIN_MAX + 1) * 4;
    float* nout  = (float*)base;  base += (size_t)N * 4;
    float* nin9  = (float*)base;  base += (size_t)N * 4;
    int*   rowptr = (int*)base;   base += ((size_t)N + 1) * 4;
    float* wpart = (float*)base;  base += (size_t)P * npb * 4;
    float* beta  = (float*)base;

    unsigned char* bss = (unsigned char*)ssrc; // dead before ssrc written

    float* x = (float*)d_out; // relu(h) lives in d_out until final_k

    relu_k<<<(n4 + 255) / 256, 256, 0, stream>>>((const float4*)h, (float4*)x, n4);

    for (int p = 0; p < P; ++p) {
        const int* sp = src + (size_t)p * E;
        const int* dp = dst + (size_t)p * E;
        float* zp = z + (size_t)p * NF;
        unsigned int* bsd = (unsigned int*)zp; // zp dead until step-2 writes it

        binA_k<<<NBLK, 256, 0, stream>>>(sp, dp, cntD, cntS, E, nbin, chunk);
        dim3 gB1(nbin, 2);
        binB1_k<<<gB1, NBLK, 0, stream>>>(cntD, cntS, totD, totS, nbin);
        binB2_k<<<1, NBIN_MAX, 0, stream>>>(totD, totS, startD, startS, nbin, E);
        binC_k<<<NBLK, 256, 0, stream>>>(sp, dp, cntD, cntS, startD, startS, bsd, bss, E, nbin, chunk);
        outdeg_k<<<nbin, 256, 0, stream>>>(bss, startS, nout, N);
        csr_k<<<nbin, 256, 0, stream>>>(bsd, startD, ssrc, rowptr, nin9, N, E);

        prescale_k<<<(n4 + 255) / 256, 256, 0, stream>>>((const float4*)x, nout, (float4*)featA, n4);

        int pgrid = (N + 3) / 4;
        pull2_k<<<pgrid, 256, 0, stream>>>(rowptr, ssrc, featA, x, nin9, nout, featB, N, 1);
        pull2_k<<<pgrid, 256, 0, stream>>>(rowptr, ssrc, featB, x, nin9, nout, featA, N, 1);
        pull2_k<<<pgrid, 256, 0, stream>>>(rowptr, ssrc, featA, x, nin9, nout, zp,    N, 0);
    }

    dim3 fgrid(npb, P);
    fusion_mfma_k<<<fgrid, 256, 0, stream>>>(z, W1, b1, W2, wpart, N, nTiles, npb);
    beta2_k<<<1, 256, 0, stream>>>(wpart, beta, npb, 1.0f / (float)N);
    final_k<<<(n4 + 255) / 256, 256, 0, stream>>>((const float4*)z, beta, (float4*)d_out, n4, NF / 4);
}

// Round 8
// 1283.298 us; speedup vs baseline: 10.1811x; 1.2495x over previous
//
#include <hip/hip_runtime.h>
#include <hip/hip_fp16.h>

#define D 64            // FEAT
#define BSH 7           // bin shift
#define BW_ 128         // nodes per bin
#define NBLK 256        // binning blocks
#define NBIN_MAX 1024   // supports N <= 131072

typedef __attribute__((ext_vector_type(8))) short bfrag;   // 8 bf16 (4 VGPR)
typedef __attribute__((ext_vector_type(4))) float ffrag;   // 4 f32 acc
typedef __attribute__((ext_vector_type(4))) _Float16 h4;   // 4 f16 (8B)

__device__ __forceinline__ short f2bf(float f) {
    unsigned u = __builtin_bit_cast(unsigned, f);
    u = (u + 0x7FFFu + ((u >> 16) & 1u)) >> 16;   // RNE
    return (short)u;
}
__device__ __forceinline__ float tanh_fast(float x) {
    float e = __expf(2.0f * x);
    return 1.0f - 2.0f / (e + 1.0f);   // exact limits at +-inf
}

// ---------------------------------------------------------------- relu -> f16: xh = (f16)max(h,0)
__global__ void reluh_k(const float4* __restrict__ h, h4* __restrict__ xh, int n4) {
    int i = blockIdx.x * blockDim.x + threadIdx.x;
    if (i < n4) {
        float4 v = h[i];
        h4 o;
        o[0] = (_Float16)fmaxf(v.x, 0.f);
        o[1] = (_Float16)fmaxf(v.y, 0.f);
        o[2] = (_Float16)fmaxf(v.z, 0.f);
        o[3] = (_Float16)fmaxf(v.w, 0.f);
        xh[i] = o;
    }
}

// ---------------------------------------------------------------- pass A: per-block coarse histograms (dst-bin AND src-bin)
__global__ void binA_k(const int* __restrict__ src, const int* __restrict__ dst,
                       int* __restrict__ cntD, int* __restrict__ cntS,
                       int E, int nbin, int chunk) {
    __shared__ int hD[NBIN_MAX], hS[NBIN_MAX];
    int tid = threadIdx.x, b = blockIdx.x;
    for (int i = tid; i < nbin; i += 256) { hD[i] = 0; hS[i] = 0; }
    __syncthreads();
    int k1 = min(E, (b + 1) * chunk);
    for (int k = b * chunk + tid; k < k1; k += 256) {
        atomicAdd(&hD[dst[k] >> BSH], 1);
        atomicAdd(&hS[src[k] >> BSH], 1);
    }
    __syncthreads();
    for (int i = tid; i < nbin; i += 256) {
        cntD[i * NBLK + b] = hD[i];
        cntS[i * NBLK + b] = hS[i];
    }
}

// ---------------------------------------------------------------- pass B1: per-bin exclusive scan over blocks (+ totals)
__global__ void binB1_k(int* __restrict__ cntD, int* __restrict__ cntS,
                        int* __restrict__ totD, int* __restrict__ totS, int nbin) {
    int bin = blockIdx.x, tid = threadIdx.x;
    int* cnt = blockIdx.y ? cntS : cntD;
    int* tot = blockIdx.y ? totS : totD;
    __shared__ int tmp[NBLK];
    int v = cnt[bin * NBLK + tid];
    tmp[tid] = v;
    __syncthreads();
    for (int off = 1; off < NBLK; off <<= 1) {
        int t = (tid >= off) ? tmp[tid - off] : 0;
        __syncthreads();
        tmp[tid] += t;
        __syncthreads();
    }
    cnt[bin * NBLK + tid] = tmp[tid] - v;
    if (tid == NBLK - 1) tot[bin] = tmp[tid];
}

// ---------------------------------------------------------------- pass B2: scan bin totals -> bin starts (+sentinel)
__global__ void binB2_k(const int* __restrict__ totD, const int* __restrict__ totS,
                        int* __restrict__ startD, int* __restrict__ startS,
                        int nbin, int E) {
    __shared__ int tmp[NBIN_MAX];
    int tid = threadIdx.x; // 1024
    {
        int v = (tid < nbin) ? totD[tid] : 0;
        tmp[tid] = v;
        __syncthreads();
        for (int off = 1; off < NBIN_MAX; off <<= 1) {
            int t = (tid >= off) ? tmp[tid - off] : 0;
            __syncthreads();
            tmp[tid] += t;
            __syncthreads();
        }
        if (tid < nbin) startD[tid] = tmp[tid] - v;
        if (tid == 0) startD[nbin] = E;
        __syncthreads();
    }
    {
        int v = (tid < nbin) ? totS[tid] : 0;
        tmp[tid] = v;
        __syncthreads();
        for (int off = 1; off < NBIN_MAX; off <<= 1) {
            int t = (tid >= off) ? tmp[tid - off] : 0;
            __syncthreads();
            tmp[tid] += t;
            __syncthreads();
        }
        if (tid < nbin) startS[tid] = tmp[tid] - v;
        if (tid == 0) startS[nbin] = E;
    }
}

// ---------------------------------------------------------------- pass C: scatter edges into bins (LDS fill counters only)
__global__ void binC_k(const int* __restrict__ src, const int* __restrict__ dst,
                       const int* __restrict__ cntD, const int* __restrict__ cntS,
                       const int* __restrict__ startD, const int* __restrict__ startS,
                       unsigned int* __restrict__ bsd, unsigned char* __restrict__ bss,
                       int E, int nbin, int chunk) {
    __shared__ int baseD[NBIN_MAX], baseS[NBIN_MAX];
    int tid = threadIdx.x, b = blockIdx.x;
    for (int i = tid; i < nbin; i += 256) {
        baseD[i] = startD[i] + cntD[i * NBLK + b];
        baseS[i] = startS[i] + cntS[i * NBLK + b];
    }
    __syncthreads();
    int k1 = min(E, (b + 1) * chunk);
    for (int k = b * chunk + tid; k < k1; k += 256) {
        int s = src[k], d = dst[k];
        int pD = atomicAdd(&baseD[d >> BSH], 1);
        bsd[pD] = (unsigned)s | ((unsigned)(d & (BW_ - 1)) << 17);
        int pS = atomicAdd(&baseS[s >> BSH], 1);
        bss[pS] = (unsigned char)(s & (BW_ - 1));
    }
}

// ---------------------------------------------------------------- out-degree -> norm_out
__global__ void outdeg_k(const unsigned char* __restrict__ bss, const int* __restrict__ startS,
                         float* __restrict__ nout, int N) {
    int b = blockIdx.x, tid = threadIdx.x;
    __shared__ int h[BW_];
    if (tid < BW_) h[tid] = 0;
    __syncthreads();
    int k1 = startS[b + 1];
    for (int k = startS[b] + tid; k < k1; k += 256) atomicAdd(&h[bss[k]], 1);
    __syncthreads();
    if (tid < BW_) {
        int n = b * BW_ + tid;
        if (n < N) nout[n] = rsqrtf(fmaxf((float)h[tid], 1.0f));
    }
}

// ---------------------------------------------------------------- per-bin counting sort -> true CSR
__global__ void csr_k(const unsigned int* __restrict__ bsd, const int* __restrict__ startD,
                      int* __restrict__ ssrc, int* __restrict__ rowptr,
                      float* __restrict__ nin9, int N, int E) {
    __shared__ int hist[BW_], tmp[BW_], excl[BW_], fill[BW_];
    int b = blockIdx.x, tid = threadIdx.x;
    if (tid < BW_) { hist[tid] = 0; fill[tid] = 0; }
    __syncthreads();
    int kb = startD[b], ke = startD[b + 1];
    for (int k = kb + tid; k < ke; k += 256) atomicAdd(&hist[bsd[k] >> 17], 1);
    __syncthreads();
    if (tid < BW_) tmp[tid] = hist[tid];
    __syncthreads();
    for (int off = 1; off < BW_; off <<= 1) {
        int t = (tid < BW_ && tid >= off) ? tmp[tid - off] : 0;
        __syncthreads();
        if (tid < BW_) tmp[tid] += t;
        __syncthreads();
    }
    if (tid < BW_) excl[tid] = tmp[tid] - hist[tid];
    __syncthreads();
    for (int k = kb + tid; k < ke; k += 256) {
        unsigned e = bsd[k];
        int dl = e >> 17;
        int r = atomicAdd(&fill[dl], 1);
        ssrc[kb + excl[dl] + r] = (int)(e & 0x1FFFF);
    }
    if (tid < BW_) {
        int n = b * BW_ + tid;
        if (n < N) {
            rowptr[n] = kb + excl[tid];
            nin9[n] = 0.9f * rsqrtf(fmaxf((float)hist[tid], 1.0f));
        }
    }
    if (b == 0 && tid == 0) rowptr[N] = E;
}

// ---------------------------------------------------------------- featS = nout[node] * xh  (f16 in/out)
__global__ void prescaleh_k(const h4* __restrict__ in, const float* __restrict__ nout,
                            h4* __restrict__ out, int n4) {
    int i = blockIdx.x * blockDim.x + threadIdx.x;
    if (i < n4) {
        float w = nout[i >> 4]; // 16 h4 per node
        h4 v = in[i];
        h4 o;
        o[0] = (_Float16)(w * (float)v[0]);
        o[1] = (_Float16)(w * (float)v[1]);
        o[2] = (_Float16)(w * (float)v[2]);
        o[3] = (_Float16)(w * (float)v[3]);
        out[i] = o;
    }
}

// ---------------------------------------------------------------- CSR pull (f16 gather): one wave/node, 8 edges in flight
// raw = sum_e featS[src_e]; r = nin9*raw + 0.1*xh; steps 1-2: outH = nout*r (f16); step 3: outF = r (f32)
__global__ void pull2h_k(const int* __restrict__ rowptr, const int* __restrict__ ssrc,
                         const h4* __restrict__ featS, const h4* __restrict__ xh,
                         const float* __restrict__ nin9, const float* __restrict__ nout,
                         h4* __restrict__ outH, float* __restrict__ outF, int N, int doScale) {
    int wid = (blockIdx.x * blockDim.x + threadIdx.x) >> 6;
    if (wid >= N) return;
    int lane = threadIdx.x & 63;
    int slot = lane >> 4;           // 0..3
    int fq = lane & 15;             // h4 index within row (16 h4 = 64 feats)
    int kb = rowptr[wid], ke = rowptr[wid + 1];
    float a0 = 0.f, a1 = 0.f, a2 = 0.f, a3 = 0.f;
    int k = kb + slot;
    for (; k + 4 < ke; k += 8) {    // 2 edges per slot in flight
        int s0 = ssrc[k], s1 = ssrc[k + 4];
        h4 f0 = featS[(size_t)s0 * 16 + fq];
        h4 f1 = featS[(size_t)s1 * 16 + fq];
        a0 += (float)f0[0] + (float)f1[0];
        a1 += (float)f0[1] + (float)f1[1];
        a2 += (float)f0[2] + (float)f1[2];
        a3 += (float)f0[3] + (float)f1[3];
    }
    if (k < ke) {
        int s = ssrc[k];
        h4 f = featS[(size_t)s * 16 + fq];
        a0 += (float)f[0]; a1 += (float)f[1]; a2 += (float)f[2]; a3 += (float)f[3];
    }
    a0 += __shfl_xor(a0, 16, 64); a1 += __shfl_xor(a1, 16, 64);
    a2 += __shfl_xor(a2, 16, 64); a3 += __shfl_xor(a3, 16, 64);
    a0 += __shfl_xor(a0, 32, 64); a1 += __shfl_xor(a1, 32, 64);
    a2 += __shfl_xor(a2, 32, 64); a3 += __shfl_xor(a3, 32, 64);
    if (slot == 0) {
        size_t gi = (size_t)wid * 16 + fq;
        h4 xv = xh[gi];
        float nn = nin9[wid];
        float r0 = nn * a0 + 0.1f * (float)xv[0];
        float r1 = nn * a1 + 0.1f * (float)xv[1];
        float r2 = nn * a2 + 0.1f * (float)xv[2];
        float r3 = nn * a3 + 0.1f * (float)xv[3];
        if (doScale) {
            float sc = nout[wid];
            h4 o;
            o[0] = (_Float16)(sc * r0); o[1] = (_Float16)(sc * r1);
            o[2] = (_Float16)(sc * r2); o[3] = (_Float16)(sc * r3);
            outH[gi] = o;
        } else {
            float4 o4; o4.x = r0; o4.y = r1; o4.z = r2; o4.w = r3;
            *(float4*)(outF + (size_t)wid * D + (fq << 2)) = o4;
        }
    }
}

// ---------------------------------------------------------------- fusion via MFMA: one wave per 16-node tile, all 128 hidden
__global__ void fusion_mfma_k(const float* __restrict__ z, const float* __restrict__ W1,
                              const float* __restrict__ b1v, const float* __restrict__ W2,
                              float* __restrict__ wpart, int N, int nTiles, int npb) {
    int p = blockIdx.y;
    int wv = threadIdx.x >> 6;
    int lane = threadIdx.x & 63;
    int tile = blockIdx.x * 4 + wv;
    float part = 0.0f;
    if (tile < nTiles) {
        int r = lane & 15;      // A row (node) / B,D col (hidden)
        int g = lane >> 4;      // k-group
        size_t node_a = (size_t)tile * 16 + r;
        if (node_a >= (size_t)N) node_a = N - 1;   // tail clamp (masked below)
        const float* zr = z + ((size_t)p * N + node_a) * 64 + g * 8;
        float4 v0 = *(const float4*)(zr);
        float4 v1 = *(const float4*)(zr + 4);
        float4 v2 = *(const float4*)(zr + 32);
        float4 v3 = *(const float4*)(zr + 36);
        bfrag a0, a1;
        a0[0] = f2bf(v0.x); a0[1] = f2bf(v0.y); a0[2] = f2bf(v0.z); a0[3] = f2bf(v0.w);
        a0[4] = f2bf(v1.x); a0[5] = f2bf(v1.y); a0[6] = f2bf(v1.z); a0[7] = f2bf(v1.w);
        a1[0] = f2bf(v2.x); a1[1] = f2bf(v2.y); a1[2] = f2bf(v2.z); a1[3] = f2bf(v2.w);
        a1[4] = f2bf(v3.x); a1[5] = f2bf(v3.y); a1[6] = f2bf(v3.z); a1[7] = f2bf(v3.w);
#pragma unroll 2
        for (int ct = 0; ct < 8; ++ct) {
            int j = ct * 16 + r;
            const float* wp = W1 + (size_t)(g * 8) * 128 + j;   // W1[k][j], k = g*8+e
            bfrag b0, b1f;
#pragma unroll
            for (int e = 0; e < 8; ++e) {
                b0[e]  = f2bf(wp[e * 128]);
                b1f[e] = f2bf(wp[(e + 32) * 128]);
            }
            ffrag acc = {0.f, 0.f, 0.f, 0.f};
            acc = __builtin_amdgcn_mfma_f32_16x16x32_bf16(a0, b0, acc, 0, 0, 0);
            acc = __builtin_amdgcn_mfma_f32_16x16x32_bf16(a1, b1f, acc, 0, 0, 0);
            float bb = b1v[j], w2 = W2[j];
#pragma unroll
            for (int q = 0; q < 4; ++q) {                        // D row = g*4+q
                int node = tile * 16 + g * 4 + q;
                if (node < N) part += w2 * tanh_fast(acc[q] + bb);
            }
        }
    }
#pragma unroll
    for (int off = 1; off < 64; off <<= 1) part += __shfl_xor(part, off, 64);
    __shared__ float ps[4];
    if (lane == 0) ps[wv] = part;
    __syncthreads();
    if (threadIdx.x == 0)
        wpart[(size_t)p * npb + blockIdx.x] = ps[0] + ps[1] + ps[2] + ps[3];
}

// ---------------------------------------------------------------- reduce partials -> beta = softmax(mean)
__global__ void beta2_k(const float* __restrict__ wpart, float* __restrict__ beta,
                        int npb, float invN) {
    int tid = threadIdx.x; // 256
    __shared__ float sums[3];
    __shared__ float ws4[4];
    for (int p = 0; p < 3; ++p) {
        float s = 0.f;
        for (int i = tid; i < npb; i += 256) s += wpart[(size_t)p * npb + i];
#pragma unroll
        for (int off = 1; off < 64; off <<= 1) s += __shfl_xor(s, off, 64);
        if ((tid & 63) == 0) ws4[tid >> 6] = s;
        __syncthreads();
        if (tid == 0) sums[p] = ws4[0] + ws4[1] + ws4[2] + ws4[3];
        __syncthreads();
    }
    if (tid == 0) {
        float w0 = sums[0] * invN, w1 = sums[1] * invN, w2 = sums[2] * invN;
        float m = fmaxf(w0, fmaxf(w1, w2));
        float e0 = expf(w0 - m), e1 = expf(w1 - m), e2 = expf(w2 - m);
        float s = e0 + e1 + e2;
        beta[0] = e0 / s; beta[1] = e1 / s; beta[2] = e2 / s;
    }
}

// ---------------------------------------------------------------- out = sum_p beta[p] * z[p]  (float4)
__global__ void final_k(const float4* __restrict__ z, const float* __restrict__ beta,
                        float4* __restrict__ out, int n4, size_t NF4) {
    int i = blockIdx.x * blockDim.x + threadIdx.x;
    if (i < n4) {
        float b0 = beta[0], b1v = beta[1], b2 = beta[2];
        float4 z0 = z[i], z1 = z[i + NF4], z2 = z[i + 2 * NF4];
        float4 r;
        r.x = b0 * z0.x + b1v * z1.x + b2 * z2.x;
        r.y = b0 * z0.y + b1v * z1.y + b2 * z2.y;
        r.z = b0 * z0.z + b1v * z1.z + b2 * z2.z;
        r.w = b0 * z0.w + b1v * z1.w + b2 * z2.w;
        out[i] = r;
    }
}

extern "C" void kernel_launch(void* const* d_in, const int* in_sizes, int n_in,
                              void* d_out, int out_size, void* d_ws, size_t ws_size,
                              hipStream_t stream) {
    const float* h   = (const float*)d_in[0];
    const int*   src = (const int*)d_in[1];
    const int*   dst = (const int*)d_in[2];
    const float* W1  = (const float*)d_in[3];
    const float* b1  = (const float*)d_in[4];
    const float* W2  = (const float*)d_in[5];

    const int P = 3;
    const int N = in_sizes[0] / D;           // 100000
    const int E = in_sizes[1] / P;           // 3200000
    const size_t NF = (size_t)N * D;
    const int nf = (int)NF, n4 = nf / 4;
    const int nbin = (N + BW_ - 1) >> BSH;   // 782
    const int chunk = (E + NBLK - 1) / NBLK;
    const int nTiles = (N + 15) / 16;        // 6250
    const int npb = (nTiles + 3) / 4;        // fusion blocks per path

    // workspace layout (bytes)
    char* base = (char*)d_ws;
    float* z     = (float*)base;  base += 3 * NF * sizeof(float);
    h4*    featA = (h4*)base;     base += NF * 2;       // f16
    h4*    featB = (h4*)base;     base += NF * 2;       // f16
    h4*    xh    = (h4*)base;     base += NF * 2;       // f16 relu(h)
    int*   ssrc  = (int*)base;    base += (size_t)E * 4;
    int*   cntD  = (int*)base;    base += (size_t)NBIN_MAX * NBLK * 4;
    int*   cntS  = (int*)base;    base += (size_t)NBIN_MAX * NBLK * 4;
    int*   totD  = (int*)base;    base += NBIN_MAX * 4;
    int*   totS  = (int*)base;    base += NBIN_MAX * 4;
    int*   startD = (int*)base;   base += (NBIN_MAX + 1) * 4;
    int*   startS = (int*)base;   base += (NBIN_MAX + 1) * 4;
    float* nout  = (float*)base;  base += (size_t)N * 4;
    float* nin9  = (float*)base;  base += (size_t)N * 4;
    int*   rowptr = (int*)base;   base += ((size_t)N + 1) * 4;
    float* wpart = (float*)base;  base += (size_t)P * npb * 4;
    float* beta  = (float*)base;

    unsigned char* bss = (unsigned char*)ssrc; // dead before ssrc written

    reluh_k<<<(n4 + 255) / 256, 256, 0, stream>>>((const float4*)h, xh, n4);

    for (int p = 0; p < P; ++p) {
        const int* sp = src + (size_t)p * E;
        const int* dp = dst + (size_t)p * E;
        float* zp = z + (size_t)p * NF;
        unsigned int* bsd = (unsigned int*)zp; // zp dead until step-3 writes it

        binA_k<<<NBLK, 256, 0, stream>>>(sp, dp, cntD, cntS, E, nbin, chunk);
        dim3 gB1(nbin, 2);
        binB1_k<<<gB1, NBLK, 0, stream>>>(cntD, cntS, totD, totS, nbin);
        binB2_k<<<1, NBIN_MAX, 0, stream>>>(totD, totS, startD, startS, nbin, E);
        binC_k<<<NBLK, 256, 0, stream>>>(sp, dp, cntD, cntS, startD, startS, bsd, bss, E, nbin, chunk);
        outdeg_k<<<nbin, 256, 0, stream>>>(bss, startS, nout, N);
        csr_k<<<nbin, 256, 0, stream>>>(bsd, startD, ssrc, rowptr, nin9, N, E);

        prescaleh_k<<<(n4 + 255) / 256, 256, 0, stream>>>(xh, nout, featA, n4);

        int pgrid = (N + 3) / 4; // 4 waves (nodes) per 256-thread block
        pull2h_k<<<pgrid, 256, 0, stream>>>(rowptr, ssrc, featA, xh, nin9, nout, featB, nullptr, N, 1);
        pull2h_k<<<pgrid, 256, 0, stream>>>(rowptr, ssrc, featB, xh, nin9, nout, featA, nullptr, N, 1);
        pull2h_k<<<pgrid, 256, 0, stream>>>(rowptr, ssrc, featA, xh, nin9, nout, nullptr, zp, N, 0);
    }

    dim3 fgrid(npb, P);
    fusion_mfma_k<<<fgrid, 256, 0, stream>>>(z, W1, b1, W2, wpart, N, nTiles, npb);
    beta2_k<<<1, 256, 0, stream>>>(wpart, beta, npb, 1.0f / (float)N);
    final_k<<<(n4 + 255) / 256, 256, 0, stream>>>((const float4*)z, beta, (float4*)d_out, n4, NF / 4);
}